// Round 4
// baseline (320.661 us; speedup 1.0000x reference)
//
#include <hip/hip_runtime.h>

// MultiScaleRoIAlign: 4 FPN levels (fp32 NCHW), 512 RoIs, 7x7 out, SR=2,
// aligned=False, torchvision semantics. Only the assigned level is computed.
//
// R4: LDS region staging (R3) + fix: outer column-chunk loop so regions
// wider than one wave-chunk (pw up to ~130 for extreme-aspect RoIs) are
// fully staged. Common case (pw <= chunk) is identical to R3's single pass.

#define NBINS 49
#define NCH 256
#define RPB 256
#define CPW 16            // channels per wave
#define CAPF 1600         // per-wave region capacity (floats); worst case ~1100

__global__ __launch_bounds__(256) void msroi_kernel(
    const float* __restrict__ f0, const float* __restrict__ f1,
    const float* __restrict__ f2, const float* __restrict__ f3,
    const float* __restrict__ boxes0, const float* __restrict__ boxes1,
    float* __restrict__ out)
{
    __shared__ float regbuf[4 * CAPF + 64];   // 4 wave buffers + guard

    const int r    = blockIdx.x;       // roi 0..511
    const int q    = blockIdx.y;       // channel quarter 0..3
    const int tid  = threadIdx.x;
    const int lane = tid & 63;
    const int wid  = tid >> 6;
    const int c0   = q * 64 + wid * CPW;

    // ---- per-roi metadata (uniform across block) ----
    const int b = (r < RPB) ? 0 : 1;
    const float* bx = (b == 0) ? (boxes0 + (size_t)r * 4)
                               : (boxes1 + (size_t)(r - RPB) * 4);
    const float x1b = bx[0], y1b = bx[1], x2b = bx[2], y2b = bx[3];

    const float area = (x2b - x1b) * (y2b - y1b);
    const float s    = sqrtf(area);
    const float tgt  = floorf(4.0f + log2f(s / 224.0f) + 1e-6f);
    const float lvlf = fminf(fmaxf(tgt, 2.0f), 5.0f);
    const int   lvl  = (int)lvlf - 2;          // 0..3

    int H, W;
    const float* feat;
    float scale;
    switch (lvl) {
      case 0:  feat = f0; H = 200; W = 200; scale = 0.25f;    break;
      case 1:  feat = f1; H = 100; W = 100; scale = 0.125f;   break;
      case 2:  feat = f2; H = 50;  W = 50;  scale = 0.0625f;  break;
      default: feat = f3; H = 25;  W = 25;  scale = 0.03125f; break;
    }
    const int HW = H * W;

    const float x1 = x1b * scale, y1 = y1b * scale;
    const float x2 = x2b * scale, y2 = y2b * scale;
    const float roi_w = fmaxf(x2 - x1, 1.0f);
    const float roi_h = fmaxf(y2 - y1, 1.0f);
    const float bin_w = roi_w / 7.0f;
    const float bin_h = roi_h / 7.0f;

    // identical expression used for both region bounds and taps
    auto ycoord = [&](int i) { return y1 + (((float)i + 0.5f) * 0.5f) * bin_h; };
    auto xcoord = [&](int i) { return x1 + (((float)i + 0.5f) * 0.5f) * bin_w; };

    // ---- region bounds (uniform). Samples are monotone in i. ----
    const int yl_min = min((int)fmaxf(ycoord(0),  0.0f), H - 1);
    const int yl_max = min((int)fmaxf(ycoord(13), 0.0f), H - 1);
    const int xl_min = min((int)fmaxf(xcoord(0),  0.0f), W - 1);
    const int xl_max = min((int)fmaxf(xcoord(13), 0.0f), W - 1);
    const int y0 = yl_min;
    const int x0 = xl_min;
    const int ph = min(yl_max + 1, H - 1) - y0 + 1;   // staged rows
    const int pw = xl_max - x0 + 2;                   // staged cols (incl +1 pair col)
    const int pwp = pw | 1;                           // odd LDS row stride

    // staging geometry: lanes cover `chunk` cols x (64/chunk) rows per pass
    int lsh;
    if      (pw <= 8)  lsh = 3;
    else if (pw <= 16) lsh = 4;
    else if (pw <= 32) lsh = 5;
    else               lsh = 6;
    const int chunk  = 1 << lsh;
    const int rpi    = 64 >> lsh;                     // rows per instruction
    const int srow   = lane >> lsh;
    const int scol   = lane & (chunk - 1);
    const int nstage = (ph + rpi - 1) >> (6 - lsh);   // ceil(ph / rpi)

    // ---- per-lane taps: 8 LDS indices + 16 weights, once per RoI ----
    const bool active = (lane < NBINS);
    const int  binid  = active ? lane : 0;
    const int  oh = binid / 7, ow = binid % 7;

    int   iA[4], iB[4];
    float w00[4], w01[4], w10[4], w11[4];
    #pragma unroll
    for (int sy = 0; sy < 2; ++sy) {
      const float yy = ycoord(oh * 2 + sy);
      const float vy = (yy > -1.0f && yy < (float)H) ? 1.0f : 0.0f;
      const float yc = fmaxf(yy, 0.0f);
      const int   yl = min((int)yc, H - 1);
      const int   yh = min(yl + 1, H - 1);
      const float fy = (yl >= H - 1) ? 0.0f : (yc - (float)yl);
      #pragma unroll
      for (int sx = 0; sx < 2; ++sx) {
        const float xx = xcoord(ow * 2 + sx);
        const float vx = (xx > -1.0f && xx < (float)W) ? 1.0f : 0.0f;
        const float xc = fmaxf(xx, 0.0f);
        const int   xl = min((int)xc, W - 1);
        const float fx = (xl >= W - 1) ? 0.0f : (xc - (float)xl);
        const int   sI = sy * 2 + sx;
        const float vv = vy * vx * 0.25f;             // fold the /4 sample mean
        iA[sI] = (yl - y0) * pwp + (xl - x0);         // row yl, col pair (xl, xl+1)
        iB[sI] = (yh - y0) * pwp + (xl - x0);         // row yh
        w00[sI] = vv * (1.0f - fy) * (1.0f - fx);
        w01[sI] = vv * (1.0f - fy) * fx;
        w10[sI] = vv * fy * (1.0f - fx);
        w11[sI] = vv * fy * fx;
        if (!active) {
          iA[sI] = 0; iB[sI] = 0;
          w00[sI] = w01[sI] = w10[sI] = w11[sI] = 0.0f;
        }
      }
    }

    // ---- channel loop: stage region -> 16 LDS taps ----
    const float* fb = feat + (size_t)b * NCH * HW + (size_t)c0 * HW;
    float* ob = out + (size_t)r * (NCH * NBINS) + (size_t)c0 * NBINS;
    float* wbuf = regbuf + wid * CAPF;

    for (int ci = 0; ci < CPW; ++ci) {
      const float* fc = fb + (size_t)ci * HW;

      // stage the full region: outer loop over column chunks (pw may be >chunk)
      for (int cc = 0; cc < pw; cc += chunk) {
        const int col = cc + scol;
        const bool cw = (col < pw);
        const int sxc = min(x0 + min(col, pw - 1), W - 1);  // clamp (dup col / inactive)
        for (int i = 0; i < nstage; ++i) {
          const int rr = min(i * rpi + srow, ph - 1);       // dup last row (same data)
          const float v = fc[(y0 + rr) * W + sxc];
          if (cw) wbuf[rr * pwp + col] = v;
        }
      }
      // wave-private LDS; DS ops are in-order per wave. Fence keeps the
      // compiler from reordering and forces write completion.
      asm volatile("s_waitcnt lgkmcnt(0)" ::: "memory");

      float acc = 0.0f;
      #pragma unroll
      for (int sI = 0; sI < 4; ++sI) {
        const float a0 = wbuf[iA[sI]];
        const float a1 = wbuf[iA[sI] + 1];
        const float b0 = wbuf[iB[sI]];
        const float b1 = wbuf[iB[sI] + 1];
        acc += w00[sI] * a0 + w01[sI] * a1 + w10[sI] * b0 + w11[sI] * b1;
      }
      if (active) ob[(size_t)ci * NBINS + binid] = acc;
    }
}

extern "C" void kernel_launch(void* const* d_in, const int* in_sizes, int n_in,
                              void* d_out, int out_size, void* d_ws, size_t ws_size,
                              hipStream_t stream) {
    const float* f0 = (const float*)d_in[0];
    const float* f1 = (const float*)d_in[1];
    const float* f2 = (const float*)d_in[2];
    const float* f3 = (const float*)d_in[3];
    const float* b0 = (const float*)d_in[4];
    const float* b1 = (const float*)d_in[5];
    float* out = (float*)d_out;

    msroi_kernel<<<dim3(512, 4), dim3(256), 0, stream>>>(f0, f1, f2, f3, b0, b1, out);
}

// Round 7
// 247.326 us; speedup vs baseline: 1.2965x; 1.2965x over previous
//
#include <hip/hip_runtime.h>

// MultiScaleRoIAlign: 4 FPN levels (fp32), 512 RoIs, 7x7 out, SR=2,
// aligned=False, torchvision semantics. Only the assigned level is computed.
//
// R7 (= R6, resubmitted after infra timeouts): two-phase. Phase 1: NCHW->NHWC
// transpose of all levels into d_ws (LDS-tiled, coalesced both sides).
// Phase 2: lanes->channels; every tap is ONE fully-coalesced dwordx4
// wave-load covering all 256 channels (no gather).

#define NBINS 49
#define NCH 256
#define RPB 256

// NHWC level bases in floats within d_ws
#define OFS0 0
#define OFS1 20480000      // 2*200*200*256
#define OFS2 25600000      // + 2*100*100*256
#define OFS3 26880000      // + 2*50*50*256
#define WS_FLOATS 27200000 // + 2*25*25*256

// ---------------- Phase 1: NCHW -> NHWC transpose (one level) ----------------
__global__ __launch_bounds__(256) void transpose_kernel(
    const float* __restrict__ src, float* __restrict__ dst, int HW)
{
    __shared__ float tile[64 * 65];
    const int tid  = threadIdx.x;
    const int lane = tid & 63;
    const int wid  = tid >> 6;
    const int hw0  = blockIdx.x * 64;
    const int c0   = blockIdx.y * 64;
    const int b    = blockIdx.z;

    const float* sp = src + ((size_t)b * NCH + c0) * HW + hw0;
    const bool inb = (hw0 + lane) < HW;
    #pragma unroll
    for (int i = 0; i < 16; ++i) {
        const int cl = wid * 16 + i;
        float v = 0.0f;
        if (inb) v = sp[(size_t)cl * HW + lane];
        tile[cl * 65 + lane] = v;
    }
    __syncthreads();
    float* dp = dst + ((size_t)b * HW + hw0) * NCH + c0;
    #pragma unroll
    for (int k = 0; k < 16; ++k) {
        const int hl = wid * 16 + k;
        if (hw0 + hl < HW)
            dp[(size_t)hl * NCH + lane] = tile[lane * 65 + hl];
    }
}

// ---------------- Phase 2: RoIAlign on NHWC ----------------
// grid (512 rois, 2 bin-halves), 256 threads. Lane l owns channels [4l,4l+4).
__global__ __launch_bounds__(256) void roi_nhwc_kernel(
    const float* __restrict__ ws,
    const float* __restrict__ boxes0, const float* __restrict__ boxes1,
    float* __restrict__ out)
{
    __shared__ float lds_out[25 * 257];

    const int r    = blockIdx.x;
    const int half = blockIdx.y;
    const int tid  = threadIdx.x;
    const int lane = tid & 63;
    const int wid  = tid >> 6;

    // ---- per-roi metadata (uniform across block) ----
    const int b = (r < RPB) ? 0 : 1;
    const float* bx = (b == 0) ? (boxes0 + (size_t)r * 4)
                               : (boxes1 + (size_t)(r - RPB) * 4);
    const float x1b = bx[0], y1b = bx[1], x2b = bx[2], y2b = bx[3];

    const float area = (x2b - x1b) * (y2b - y1b);
    const float s    = sqrtf(area);
    const float tgt  = floorf(4.0f + log2f(s / 224.0f) + 1e-6f);
    const float lvlf = fminf(fmaxf(tgt, 2.0f), 5.0f);
    const int   lvl  = (int)lvlf - 2;          // 0..3

    int H, W; size_t base; float scale;
    switch (lvl) {
      case 0:  base = OFS0; H = 200; W = 200; scale = 0.25f;    break;
      case 1:  base = OFS1; H = 100; W = 100; scale = 0.125f;   break;
      case 2:  base = OFS2; H = 50;  W = 50;  scale = 0.0625f;  break;
      default: base = OFS3; H = 25;  W = 25;  scale = 0.03125f; break;
    }

    const float x1 = x1b * scale, y1 = y1b * scale;
    const float x2 = x2b * scale, y2 = y2b * scale;
    const float roi_w = fmaxf(x2 - x1, 1.0f);
    const float roi_h = fmaxf(y2 - y1, 1.0f);
    const float bin_w = roi_w / 7.0f;
    const float bin_h = roi_h / 7.0f;

    const float* fb = ws + base + (size_t)b * H * W * NCH;
    const int lc = 4 * lane;                  // this lane's first channel

    const int bin0 = half * 25;
    const int nb   = half ? 24 : 25;

    for (int bi = wid; bi < nb; bi += 4) {
        const int bin = bin0 + bi;
        const int oh = bin / 7, ow = bin % 7;
        float a0 = 0.0f, a1 = 0.0f, a2 = 0.0f, a3 = 0.0f;

        #pragma unroll
        for (int sy = 0; sy < 2; ++sy) {
            const float yy = y1 + ((float)(oh * 2 + sy) + 0.5f) * 0.5f * bin_h;
            const float vy = (yy > -1.0f && yy < (float)H) ? 1.0f : 0.0f;
            const float yc = fmaxf(yy, 0.0f);
            const int   yl = min((int)yc, H - 1);
            const int   yh = min(yl + 1, H - 1);
            const float fy = (yl >= H - 1) ? 0.0f : (yc - (float)yl);
            #pragma unroll
            for (int sx = 0; sx < 2; ++sx) {
                const float xx = x1 + ((float)(ow * 2 + sx) + 0.5f) * 0.5f * bin_w;
                const float vx = (xx > -1.0f && xx < (float)W) ? 1.0f : 0.0f;
                const float xc = fmaxf(xx, 0.0f);
                const int   xl = min((int)xc, W - 1);
                const int   xh = min(xl + 1, W - 1);
                const float fx = (xl >= W - 1) ? 0.0f : (xc - (float)xl);
                const float vv  = vy * vx * 0.25f;     // fold sample mean
                const float w00 = vv * (1.0f - fy) * (1.0f - fx);
                const float w01 = vv * (1.0f - fy) * fx;
                const float w10 = vv * fy * (1.0f - fx);
                const float w11 = vv * fy * fx;

                const float4 v00 = *(const float4*)(fb + ((size_t)(yl * W + xl)) * NCH + lc);
                const float4 v01 = *(const float4*)(fb + ((size_t)(yl * W + xh)) * NCH + lc);
                const float4 v10 = *(const float4*)(fb + ((size_t)(yh * W + xl)) * NCH + lc);
                const float4 v11 = *(const float4*)(fb + ((size_t)(yh * W + xh)) * NCH + lc);

                a0 += w00 * v00.x + w01 * v01.x + w10 * v10.x + w11 * v11.x;
                a1 += w00 * v00.y + w01 * v01.y + w10 * v10.y + w11 * v11.y;
                a2 += w00 * v00.z + w01 * v01.z + w10 * v10.z + w11 * v11.z;
                a3 += w00 * v00.w + w01 * v01.w + w10 * v10.w + w11 * v11.w;
            }
        }
        const int lb = bi * 257 + lc;
        lds_out[lb + 0] = a0;
        lds_out[lb + 1] = a1;
        lds_out[lb + 2] = a2;
        lds_out[lb + 3] = a3;
    }

    __syncthreads();

    // write out[r][c][bin0+bj] for bj in [0,nb): contiguous runs of nb floats
    const size_t obase = (size_t)r * (NCH * NBINS) + bin0;
    for (int i = tid; i < NCH * nb; i += 256) {
        const int c  = i / nb;
        const int bj = i - c * nb;
        out[obase + (size_t)c * NBINS + bj] = lds_out[bj * 257 + c];
    }
}

// ---------------- Fallback (R1-proven, 116us) if ws too small ----------------
__global__ __launch_bounds__(256) void msroi_fallback(
    const float* __restrict__ f0, const float* __restrict__ f1,
    const float* __restrict__ f2, const float* __restrict__ f3,
    const float* __restrict__ boxes0, const float* __restrict__ boxes1,
    float* __restrict__ out)
{
    __shared__ float lds_out[NCH * NBINS];
    const int r = blockIdx.x, tid = threadIdx.x;
    const int lane = tid & 63, wid = tid >> 6;
    const int b = (r < RPB) ? 0 : 1;
    const float* bx = (b == 0) ? (boxes0 + (size_t)r * 4)
                               : (boxes1 + (size_t)(r - RPB) * 4);
    const float x1b = bx[0], y1b = bx[1], x2b = bx[2], y2b = bx[3];
    const float area = (x2b - x1b) * (y2b - y1b);
    const float s = sqrtf(area);
    const float tgt = floorf(4.0f + log2f(s / 224.0f) + 1e-6f);
    const int lvl = (int)fminf(fmaxf(tgt, 2.0f), 5.0f) - 2;
    int H, W; const float* feat; float scale;
    switch (lvl) {
      case 0:  feat = f0; H = 200; W = 200; scale = 0.25f;    break;
      case 1:  feat = f1; H = 100; W = 100; scale = 0.125f;   break;
      case 2:  feat = f2; H = 50;  W = 50;  scale = 0.0625f;  break;
      default: feat = f3; H = 25;  W = 25;  scale = 0.03125f; break;
    }
    const int HW = H * W;
    const float x1 = x1b * scale, y1 = y1b * scale;
    const float x2 = x2b * scale, y2 = y2b * scale;
    const float roi_w = fmaxf(x2 - x1, 1.0f), roi_h = fmaxf(y2 - y1, 1.0f);
    const float bin_w = roi_w / 7.0f, bin_h = roi_h / 7.0f;
    const bool active = (lane < NBINS);
    const int binid = active ? lane : 0;
    const int oh = binid / 7, ow = binid % 7;
    int offs[16]; float wts[16];
    {
      int t = 0;
      #pragma unroll
      for (int sy = 0; sy < 2; ++sy) {
        const float yy = y1 + ((float)(oh * 2 + sy) + 0.5f) * 0.5f * bin_h;
        const float vy = (yy > -1.0f && yy < (float)H) ? 1.0f : 0.0f;
        const float yc = fmaxf(yy, 0.0f);
        const int yl = min((int)yc, H - 1);
        const int yh = min(yl + 1, H - 1);
        const float fy = (yl >= H - 1) ? 0.0f : (yc - (float)yl);
        const float ay0 = vy * (1.0f - fy), ay1 = vy * fy;
        #pragma unroll
        for (int sx = 0; sx < 2; ++sx) {
          const float xx = x1 + ((float)(ow * 2 + sx) + 0.5f) * 0.5f * bin_w;
          const float vx = (xx > -1.0f && xx < (float)W) ? 1.0f : 0.0f;
          const float xc = fmaxf(xx, 0.0f);
          const int xl = min((int)xc, W - 1);
          const int xh = min(xl + 1, W - 1);
          const float fx = (xl >= W - 1) ? 0.0f : (xc - (float)xl);
          const float ax0 = vx * (1.0f - fx), ax1 = vx * fx;
          offs[t] = yl * W + xl; wts[t] = ay0 * ax0; ++t;
          offs[t] = yl * W + xh; wts[t] = ay0 * ax1; ++t;
          offs[t] = yh * W + xl; wts[t] = ay1 * ax0; ++t;
          offs[t] = yh * W + xh; wts[t] = ay1 * ax1; ++t;
        }
      }
      if (!active) {
        #pragma unroll
        for (int k = 0; k < 16; ++k) { offs[k] = 0; wts[k] = 0.0f; }
      }
    }
    const float* fbb = feat + (size_t)b * NCH * HW + (size_t)wid * 64 * HW;
    for (int ci = 0; ci < 64; ++ci) {
      const float* fc = fbb + (size_t)ci * HW;
      float acc = 0.0f;
      #pragma unroll
      for (int k = 0; k < 16; ++k) acc += wts[k] * fc[offs[k]];
      if (active) lds_out[(wid * 64 + ci) * NBINS + binid] = acc * 0.25f;
    }
    __syncthreads();
    const size_t obase = (size_t)r * (NCH * NBINS);
    #pragma unroll 4
    for (int i = tid; i < NCH * NBINS; i += 256) out[obase + i] = lds_out[i];
}

extern "C" void kernel_launch(void* const* d_in, const int* in_sizes, int n_in,
                              void* d_out, int out_size, void* d_ws, size_t ws_size,
                              hipStream_t stream) {
    const float* f0 = (const float*)d_in[0];
    const float* f1 = (const float*)d_in[1];
    const float* f2 = (const float*)d_in[2];
    const float* f3 = (const float*)d_in[3];
    const float* b0 = (const float*)d_in[4];
    const float* b1 = (const float*)d_in[5];
    float* out = (float*)d_out;
    float* ws  = (float*)d_ws;

    if (ws_size >= (size_t)WS_FLOATS * 4) {
        transpose_kernel<<<dim3(625, 4, 2), 256, 0, stream>>>(f0, ws + OFS0, 40000);
        transpose_kernel<<<dim3(157, 4, 2), 256, 0, stream>>>(f1, ws + OFS1, 10000);
        transpose_kernel<<<dim3(40,  4, 2), 256, 0, stream>>>(f2, ws + OFS2, 2500);
        transpose_kernel<<<dim3(10,  4, 2), 256, 0, stream>>>(f3, ws + OFS3, 625);
        roi_nhwc_kernel<<<dim3(512, 2), 256, 0, stream>>>(ws, b0, b1, out);
    } else {
        msroi_fallback<<<dim3(512), 256, 0, stream>>>(f0, f1, f2, f3, b0, b1, out);
    }
}

// Round 8
// 216.717 us; speedup vs baseline: 1.4796x; 1.1412x over previous
//
#include <hip/hip_runtime.h>

// MultiScaleRoIAlign: 4 FPN levels (fp32), 512 RoIs, 7x7 out, SR=2,
// aligned=False, torchvision semantics. Only the assigned level is computed.
//
// R8: phase 1 rework — single merged NCHW->NHWC transpose dispatch for all
// 4 levels, float4-vectorized on both global sides (1KB/wave-instr).
// Phase 2 (roi_nhwc_kernel) unchanged from R7 (passing).

#define NBINS 49
#define NCH 256
#define RPB 256

// NHWC level bases in floats within d_ws
#define OFS0 0
#define OFS1 20480000      // 2*200*200*256
#define OFS2 25600000      // + 2*100*100*256
#define OFS3 26880000      // + 2*50*50*256
#define WS_FLOATS 27200000 // + 2*25*25*256

// merged-transpose block ranges: tiles(L)=ceil(HW/64), blocks(L)=tiles*4*2
#define TB0 5000           // 625*8
#define TB1 6256           // +157*8
#define TB2 6576           // +40*8
#define TB3 6656           // +10*8

// -------- Phase 1: merged NCHW -> NHWC transpose, float4 both sides --------
__global__ __launch_bounds__(256) void transpose_all_kernel(
    const float* __restrict__ f0, const float* __restrict__ f1,
    const float* __restrict__ f2, const float* __restrict__ f3,
    float* __restrict__ ws)
{
    __shared__ float tile[64 * 65];

    const int bid = blockIdx.x;
    const float* src; float* dst; int HW, tiles, t;
    if (bid < TB0)      { src = f0; dst = ws + OFS0; HW = 40000; tiles = 625; t = bid; }
    else if (bid < TB1) { src = f1; dst = ws + OFS1; HW = 10000; tiles = 157; t = bid - TB0; }
    else if (bid < TB2) { src = f2; dst = ws + OFS2; HW = 2500;  tiles = 40;  t = bid - TB1; }
    else                { src = f3; dst = ws + OFS3; HW = 625;   tiles = 10;  t = bid - TB2; }

    const int hwt = t % tiles;
    const int rc  = t / tiles;          // 0..7
    const int c0  = (rc & 3) * 64;
    const int b   = rc >> 2;
    const int hw0 = hwt * 64;

    const int tid  = threadIdx.x;
    const int tcol = (tid & 15) * 4;    // hw offset on read, channel offset on write
    const int trow = tid >> 4;          // 16 rows per pass

    const float* sp = src + ((size_t)b * NCH + c0) * HW + hw0;
    const bool full = (hw0 + 64 <= HW);

    #pragma unroll
    for (int p = 0; p < 4; ++p) {
        const int cl = p * 16 + trow;
        const float* row = sp + (size_t)cl * HW;
        float4 v;
        if (full) {
            v = *(const float4*)(row + tcol);
        } else {
            v.x = (hw0 + tcol + 0 < HW) ? row[tcol + 0] : 0.0f;
            v.y = (hw0 + tcol + 1 < HW) ? row[tcol + 1] : 0.0f;
            v.z = (hw0 + tcol + 2 < HW) ? row[tcol + 2] : 0.0f;
            v.w = (hw0 + tcol + 3 < HW) ? row[tcol + 3] : 0.0f;
        }
        tile[cl * 65 + tcol + 0] = v.x;
        tile[cl * 65 + tcol + 1] = v.y;
        tile[cl * 65 + tcol + 2] = v.z;
        tile[cl * 65 + tcol + 3] = v.w;
    }
    __syncthreads();

    float* dp = dst + ((size_t)b * HW + hw0) * NCH + c0;
    #pragma unroll
    for (int p = 0; p < 4; ++p) {
        const int hl = p * 16 + trow;
        if (hw0 + hl < HW) {
            float4 v;
            v.x = tile[(tcol + 0) * 65 + hl];
            v.y = tile[(tcol + 1) * 65 + hl];
            v.z = tile[(tcol + 2) * 65 + hl];
            v.w = tile[(tcol + 3) * 65 + hl];
            *(float4*)(dp + (size_t)hl * NCH + tcol) = v;
        }
    }
}

// ---------------- Phase 2: RoIAlign on NHWC (unchanged from R7) ----------------
// grid (512 rois, 2 bin-halves), 256 threads. Lane l owns channels [4l,4l+4).
__global__ __launch_bounds__(256) void roi_nhwc_kernel(
    const float* __restrict__ ws,
    const float* __restrict__ boxes0, const float* __restrict__ boxes1,
    float* __restrict__ out)
{
    __shared__ float lds_out[25 * 257];

    const int r    = blockIdx.x;
    const int half = blockIdx.y;
    const int tid  = threadIdx.x;
    const int lane = tid & 63;
    const int wid  = tid >> 6;

    // ---- per-roi metadata (uniform across block) ----
    const int b = (r < RPB) ? 0 : 1;
    const float* bx = (b == 0) ? (boxes0 + (size_t)r * 4)
                               : (boxes1 + (size_t)(r - RPB) * 4);
    const float x1b = bx[0], y1b = bx[1], x2b = bx[2], y2b = bx[3];

    const float area = (x2b - x1b) * (y2b - y1b);
    const float s    = sqrtf(area);
    const float tgt  = floorf(4.0f + log2f(s / 224.0f) + 1e-6f);
    const float lvlf = fminf(fmaxf(tgt, 2.0f), 5.0f);
    const int   lvl  = (int)lvlf - 2;          // 0..3

    int H, W; size_t base; float scale;
    switch (lvl) {
      case 0:  base = OFS0; H = 200; W = 200; scale = 0.25f;    break;
      case 1:  base = OFS1; H = 100; W = 100; scale = 0.125f;   break;
      case 2:  base = OFS2; H = 50;  W = 50;  scale = 0.0625f;  break;
      default: base = OFS3; H = 25;  W = 25;  scale = 0.03125f; break;
    }

    const float x1 = x1b * scale, y1 = y1b * scale;
    const float x2 = x2b * scale, y2 = y2b * scale;
    const float roi_w = fmaxf(x2 - x1, 1.0f);
    const float roi_h = fmaxf(y2 - y1, 1.0f);
    const float bin_w = roi_w / 7.0f;
    const float bin_h = roi_h / 7.0f;

    const float* fb = ws + base + (size_t)b * H * W * NCH;
    const int lc = 4 * lane;                  // this lane's first channel

    const int bin0 = half * 25;
    const int nb   = half ? 24 : 25;

    for (int bi = wid; bi < nb; bi += 4) {
        const int bin = bin0 + bi;
        const int oh = bin / 7, ow = bin % 7;
        float a0 = 0.0f, a1 = 0.0f, a2 = 0.0f, a3 = 0.0f;

        #pragma unroll
        for (int sy = 0; sy < 2; ++sy) {
            const float yy = y1 + ((float)(oh * 2 + sy) + 0.5f) * 0.5f * bin_h;
            const float vy = (yy > -1.0f && yy < (float)H) ? 1.0f : 0.0f;
            const float yc = fmaxf(yy, 0.0f);
            const int   yl = min((int)yc, H - 1);
            const int   yh = min(yl + 1, H - 1);
            const float fy = (yl >= H - 1) ? 0.0f : (yc - (float)yl);
            #pragma unroll
            for (int sx = 0; sx < 2; ++sx) {
                const float xx = x1 + ((float)(ow * 2 + sx) + 0.5f) * 0.5f * bin_w;
                const float vx = (xx > -1.0f && xx < (float)W) ? 1.0f : 0.0f;
                const float xc = fmaxf(xx, 0.0f);
                const int   xl = min((int)xc, W - 1);
                const int   xh = min(xl + 1, W - 1);
                const float fx = (xl >= W - 1) ? 0.0f : (xc - (float)xl);
                const float vv  = vy * vx * 0.25f;     // fold sample mean
                const float w00 = vv * (1.0f - fy) * (1.0f - fx);
                const float w01 = vv * (1.0f - fy) * fx;
                const float w10 = vv * fy * (1.0f - fx);
                const float w11 = vv * fy * fx;

                const float4 v00 = *(const float4*)(fb + ((size_t)(yl * W + xl)) * NCH + lc);
                const float4 v01 = *(const float4*)(fb + ((size_t)(yl * W + xh)) * NCH + lc);
                const float4 v10 = *(const float4*)(fb + ((size_t)(yh * W + xl)) * NCH + lc);
                const float4 v11 = *(const float4*)(fb + ((size_t)(yh * W + xh)) * NCH + lc);

                a0 += w00 * v00.x + w01 * v01.x + w10 * v10.x + w11 * v11.x;
                a1 += w00 * v00.y + w01 * v01.y + w10 * v10.y + w11 * v11.y;
                a2 += w00 * v00.z + w01 * v01.z + w10 * v10.z + w11 * v11.z;
                a3 += w00 * v00.w + w01 * v01.w + w10 * v10.w + w11 * v11.w;
            }
        }
        const int lb = bi * 257 + lc;
        lds_out[lb + 0] = a0;
        lds_out[lb + 1] = a1;
        lds_out[lb + 2] = a2;
        lds_out[lb + 3] = a3;
    }

    __syncthreads();

    // write out[r][c][bin0+bj] for bj in [0,nb): contiguous runs of nb floats
    const size_t obase = (size_t)r * (NCH * NBINS) + bin0;
    for (int i = tid; i < NCH * nb; i += 256) {
        const int c  = i / nb;
        const int bj = i - c * nb;
        out[obase + (size_t)c * NBINS + bj] = lds_out[bj * 257 + c];
    }
}

// ---------------- Fallback (R1-proven, 116us) if ws too small ----------------
__global__ __launch_bounds__(256) void msroi_fallback(
    const float* __restrict__ f0, const float* __restrict__ f1,
    const float* __restrict__ f2, const float* __restrict__ f3,
    const float* __restrict__ boxes0, const float* __restrict__ boxes1,
    float* __restrict__ out)
{
    __shared__ float lds_out[NCH * NBINS];
    const int r = blockIdx.x, tid = threadIdx.x;
    const int lane = tid & 63, wid = tid >> 6;
    const int b = (r < RPB) ? 0 : 1;
    const float* bx = (b == 0) ? (boxes0 + (size_t)r * 4)
                               : (boxes1 + (size_t)(r - RPB) * 4);
    const float x1b = bx[0], y1b = bx[1], x2b = bx[2], y2b = bx[3];
    const float area = (x2b - x1b) * (y2b - y1b);
    const float s = sqrtf(area);
    const float tgt = floorf(4.0f + log2f(s / 224.0f) + 1e-6f);
    const int lvl = (int)fminf(fmaxf(tgt, 2.0f), 5.0f) - 2;
    int H, W; const float* feat; float scale;
    switch (lvl) {
      case 0:  feat = f0; H = 200; W = 200; scale = 0.25f;    break;
      case 1:  feat = f1; H = 100; W = 100; scale = 0.125f;   break;
      case 2:  feat = f2; H = 50;  W = 50;  scale = 0.0625f;  break;
      default: feat = f3; H = 25;  W = 25;  scale = 0.03125f; break;
    }
    const int HW = H * W;
    const float x1 = x1b * scale, y1 = y1b * scale;
    const float x2 = x2b * scale, y2 = y2b * scale;
    const float roi_w = fmaxf(x2 - x1, 1.0f), roi_h = fmaxf(y2 - y1, 1.0f);
    const float bin_w = roi_w / 7.0f, bin_h = roi_h / 7.0f;
    const bool active = (lane < NBINS);
    const int binid = active ? lane : 0;
    const int oh = binid / 7, ow = binid % 7;
    int offs[16]; float wts[16];
    {
      int t = 0;
      #pragma unroll
      for (int sy = 0; sy < 2; ++sy) {
        const float yy = y1 + ((float)(oh * 2 + sy) + 0.5f) * 0.5f * bin_h;
        const float vy = (yy > -1.0f && yy < (float)H) ? 1.0f : 0.0f;
        const float yc = fmaxf(yy, 0.0f);
        const int yl = min((int)yc, H - 1);
        const int yh = min(yl + 1, H - 1);
        const float fy = (yl >= H - 1) ? 0.0f : (yc - (float)yl);
        const float ay0 = vy * (1.0f - fy), ay1 = vy * fy;
        #pragma unroll
        for (int sx = 0; sx < 2; ++sx) {
          const float xx = x1 + ((float)(ow * 2 + sx) + 0.5f) * 0.5f * bin_w;
          const float vx = (xx > -1.0f && xx < (float)W) ? 1.0f : 0.0f;
          const float xc = fmaxf(xx, 0.0f);
          const int xl = min((int)xc, W - 1);
          const int xh = min(xl + 1, W - 1);
          const float fx = (xl >= W - 1) ? 0.0f : (xc - (float)xl);
          const float ax0 = vx * (1.0f - fx), ax1 = vx * fx;
          offs[t] = yl * W + xl; wts[t] = ay0 * ax0; ++t;
          offs[t] = yl * W + xh; wts[t] = ay0 * ax1; ++t;
          offs[t] = yh * W + xl; wts[t] = ay1 * ax0; ++t;
          offs[t] = yh * W + xh; wts[t] = ay1 * ax1; ++t;
        }
      }
      if (!active) {
        #pragma unroll
        for (int k = 0; k < 16; ++k) { offs[k] = 0; wts[k] = 0.0f; }
      }
    }
    const float* fbb = feat + (size_t)b * NCH * HW + (size_t)wid * 64 * HW;
    for (int ci = 0; ci < 64; ++ci) {
      const float* fc = fbb + (size_t)ci * HW;
      float acc = 0.0f;
      #pragma unroll
      for (int k = 0; k < 16; ++k) acc += wts[k] * fc[offs[k]];
      if (active) lds_out[(wid * 64 + ci) * NBINS + binid] = acc * 0.25f;
    }
    __syncthreads();
    const size_t obase = (size_t)r * (NCH * NBINS);
    #pragma unroll 4
    for (int i = tid; i < NCH * NBINS; i += 256) out[obase + i] = lds_out[i];
}

extern "C" void kernel_launch(void* const* d_in, const int* in_sizes, int n_in,
                              void* d_out, int out_size, void* d_ws, size_t ws_size,
                              hipStream_t stream) {
    const float* f0 = (const float*)d_in[0];
    const float* f1 = (const float*)d_in[1];
    const float* f2 = (const float*)d_in[2];
    const float* f3 = (const float*)d_in[3];
    const float* b0 = (const float*)d_in[4];
    const float* b1 = (const float*)d_in[5];
    float* out = (float*)d_out;
    float* ws  = (float*)d_ws;

    if (ws_size >= (size_t)WS_FLOATS * 4) {
        transpose_all_kernel<<<dim3(TB3), 256, 0, stream>>>(f0, f1, f2, f3, ws);
        roi_nhwc_kernel<<<dim3(512, 2), 256, 0, stream>>>(ws, b0, b1, out);
    } else {
        msroi_fallback<<<dim3(512), 256, 0, stream>>>(f0, f1, f2, f3, b0, b1, out);
    }
}